// Round 3
// baseline (305.666 us; speedup 1.0000x reference)
//
#include <hip/hip_runtime.h>
#include <hip/hip_bf16.h>

// ModulatedConv2d B=16, Cin=Cout=512, 3x3, 64x64.
// out = deco[b,o] * conv2d(x*s[b,i], W*gain), weights shared across batch.
// Conv: 32x32x16 bf16 MFMA, per-wave 128(o)x64(x), 8 waves = 8 output rows,
// chunk = 16 channels, double-buffered LDS staged via global_load_lds,
// 3-phase interleave per chunk (T3/T5): reads -> barrier -> lgkm0 -> setprio MFMA.
//
// ws layout:
//   s    : f32[16*512]                 @ 0
//   deco : f32[16*512]                 @ 32768
//   q    : f32[512*512]                @ 65536
//   wb2  : bf16, frag-linear W slots   @ 1114112   (4 ot x 32 chunk x 36 (mi,t) x 64 lane x 16B)
//   xs2  : bf16, pre-swizzled X slots  @ 5832704   (16 b x 32 chunk x 64 y x 128 slots x 16B)

#define NCH 512

static constexpr float FC_GAIN_C = 0.04419417382415922f;   // 1/sqrt(512)
static constexpr float W_GAIN_C  = 0.014731391274719742f;  // 1/sqrt(512*9)

typedef float        f32x4  __attribute__((ext_vector_type(4)));
typedef float        f32x16 __attribute__((ext_vector_type(16)));
typedef short        s16x8  __attribute__((ext_vector_type(8)));
typedef unsigned int u32x4  __attribute__((ext_vector_type(4)));

__device__ __forceinline__ unsigned short f2bf(float f) {
    __hip_bfloat16 h = __float2bfloat16(f);
    return *reinterpret_cast<unsigned short*>(&h);
}

__device__ __forceinline__ void gld16(const void* g, void* l) {
    __builtin_amdgcn_global_load_lds(
        (const __attribute__((address_space(1))) unsigned int*)g,
        (__attribute__((address_space(3))) unsigned int*)(l), 16, 0, 0);
}

// ---------------- K1: s[b,i] = style[b,:] . fc_w[i,:] * FC_GAIN + fc_b[i] ----------------
__global__ void calc_s_kernel(const float* __restrict__ style,
                              const float* __restrict__ fc_w,
                              const float* __restrict__ fc_b,
                              float* __restrict__ s) {
    int gw   = (blockIdx.x * blockDim.x + threadIdx.x) >> 6;
    int lane = threadIdx.x & 63;
    int b = gw >> 9;
    int i = gw & 511;
    const float* st = style + b * NCH;
    const float* fw = fc_w + (size_t)i * NCH;
    float sum = 0.f;
    #pragma unroll
    for (int k = 0; k < NCH / 64; ++k)
        sum += st[lane + 64 * k] * fw[lane + 64 * k];
    #pragma unroll
    for (int off = 32; off >= 1; off >>= 1)
        sum += __shfl_xor(sum, off, 64);
    if (lane == 0)
        s[b * NCH + i] = sum * FC_GAIN_C + fc_b[i];
}

// ---------------- K2: q[o,i] and fragment-linear wb2 slots --------------------------------
// wb2 unit: (((ot*32+chunk)*36 + mi*9 + t)*64 + lane)*8 + e
// content: W[o = ot*128 + mi*32 + (lane&31)][ci = chunk*16 + (lane>>5)*8 + e][tap t] * gain
__global__ void calc_q_wb2_kernel(const float* __restrict__ weight,
                                  float* __restrict__ q,
                                  unsigned short* __restrict__ wb2) {
    int o = blockIdx.x;        // 0..511
    int i = threadIdx.x;       // 0..511 (ci)
    int orel = o & 127, ot = o >> 7;
    int mi = orel >> 5, l31 = orel & 31;
    int chunk = i >> 4, kk = i & 15;
    int lane = (kk >> 3) * 32 + l31, e = kk & 7;
    const float* wp = weight + ((size_t)o * NCH + i) * 9;
    float qs = 0.f;
    #pragma unroll
    for (int t = 0; t < 9; ++t) {
        float v = wp[t] * W_GAIN_C;
        qs += v * v;
        wb2[((((size_t)(ot * 32 + chunk) * 36) + mi * 9 + t) * 64 + lane) * 8 + e] = f2bf(v);
    }
    q[(size_t)o * NCH + i] = qs;
}

// ---------------- K3: deco[b,o] = rsqrt( sum_i q[o,i]*s[b,i]^2 + 1e-8 ) -----------------
__global__ void calc_deco_kernel(const float* __restrict__ q,
                                 const float* __restrict__ s,
                                 float* __restrict__ deco) {
    int gw   = (blockIdx.x * blockDim.x + threadIdx.x) >> 6;
    int lane = threadIdx.x & 63;
    int b = gw >> 9;
    int o = gw & 511;
    const float* qp = q + (size_t)o * NCH;
    const float* sp = s + b * NCH;
    float sum = 0.f;
    #pragma unroll
    for (int k = 0; k < NCH / 64; ++k) {
        float sv = sp[lane + 64 * k];
        sum += qp[lane + 64 * k] * sv * sv;
    }
    #pragma unroll
    for (int off = 32; off >= 1; off >>= 1)
        sum += __shfl_xor(sum, off, 64);
    if (lane == 0)
        deco[b * NCH + o] = rsqrtf(sum + 1e-8f);
}

// ---------------- K4: xs2 = bf16(x * s), NCHW -> per-chunk slot layout --------------------
// xs2 unit index: ((b*32+chunk)*64 + y)*128 + s ; s in [0,128): xpos = s>>1, h = s&1,
// content = x granule (ch = chunk*16 + (h ^ (((xpos+1)>>2)&1))*8 + e) at (y, xpos).
__global__ __launch_bounds__(256)
void scale_x2_kernel(const float* __restrict__ x, const float* __restrict__ s,
                     unsigned short* __restrict__ xs2) {
    __shared__ float tlf[2][64][17];
    int blk = blockIdx.x;          // 512 = bi*32 + chunk
    int chunk = blk & 31, bi = blk >> 5;
    int t = threadIdx.x;
    int ch0 = chunk * 16;
    int cl = t >> 4, xq = (t & 15) * 4;
    float sv = s[bi * NCH + ch0 + cl];
    const float* xp = x + ((size_t)(bi * NCH + ch0 + cl)) * 4096 + xq;
    int p = t >> 7, tt = t & 127;
    int xpos = tt >> 1, h = tt & 1;
    int hs = h ^ (((xpos + 1) >> 2) & 1);
    unsigned short* xout = xs2 + (size_t)(bi * 32 + chunk) * 64 * 128 * 8;
    for (int y2 = 0; y2 < 64; y2 += 2) {
        f32x4 a0 = *(const f32x4*)(xp + (size_t)y2 * 64);
        f32x4 a1 = *(const f32x4*)(xp + (size_t)(y2 + 1) * 64);
        #pragma unroll
        for (int j = 0; j < 4; ++j) {
            tlf[0][xq + j][cl] = a0[j] * sv;
            tlf[1][xq + j][cl] = a1[j] * sv;
        }
        __syncthreads();
        const float* src = &tlf[p][xpos][hs * 8];
        u32x4 v;
        #pragma unroll
        for (int j = 0; j < 4; ++j)
            v[j] = (unsigned)f2bf(src[2 * j]) | ((unsigned)f2bf(src[2 * j + 1]) << 16);
        *(u32x4*)(xout + ((size_t)(y2 + p) * 128 + tt) * 8) = v;
        __syncthreads();
    }
}

// ---------------- K5: conv, 32x32x16 MFMA, dbuf + 3-phase interleave ----------------------
// block: (bi, ot, yt) -> o-tile 128, rows y0..y0+7, 8 waves (wave = row), 512 thr.
// LDS buffer: W [36 (mi,t)][64 lane][16B] = 36864 B, X [10r][66c][16ch] = 21120 B.
#define W_SH 18432   // shorts per W buffer
#define X_SH 10560   // shorts per X buffer

#define ISSUE(nc, WN, XN)                                                          \
    {                                                                              \
        _Pragma("unroll") for (int j = 0; j < 5; ++j) {                            \
            int id = wave + j * 8;                                                 \
            if (id < 36)                                                           \
                gld16(wsrc + (((size_t)(nc) * 36 + id) * 64 + lane) * 16,          \
                      (WN) + id * 512);                                            \
        }                                                                          \
        _Pragma("unroll") for (int j = 0; j < 3; ++j) {                            \
            int id = wave + j * 8;                                                 \
            if (id < 20) {                                                         \
                int r_ = id >> 1, hf = id & 1, gy = y0 - 1 + r_;                   \
                if (gy >= 0 && gy < 64)                                            \
                    gld16(xsrc + (((size_t)(nc) * 64 + gy) * 128 + hf * 64 + lane) * 16, \
                          (XN) + r_ * 1056 + hf * 512 + 16);                       \
            }                                                                      \
        }                                                                          \
    }

#define VMBAR()                                                                    \
    {                                                                              \
        asm volatile("s_waitcnt vmcnt(0)" ::: "memory");                           \
        __builtin_amdgcn_s_barrier();                                              \
    }

// One phase: reads (18 b128) for taps 3k..3k+2, optional DMA issue, barrier,
// lgkm drain, prioritized 24-MFMA cluster.
#define PHASE(WC, XC, k, ...)                                                      \
    {                                                                              \
        s16x8 av[3][4], bv[3][2];                                                  \
        const int rr_ = wave + (k);                                                \
        _Pragma("unroll") for (int tt = 0; tt < 3; ++tt) {                         \
            const int t_ = 3 * (k) + tt;                                           \
            _Pragma("unroll") for (int mi = 0; mi < 4; ++mi)                       \
                av[tt][mi] = *(const s16x8*)((WC) + ((mi * 9 + t_) << 9) + (lane << 3)); \
            const unsigned short* bp_ = (XC) + rr_ * 1056 + boff[tt];              \
            bv[tt][0] = *(const s16x8*)bp_;                                        \
            bv[tt][1] = *(const s16x8*)(bp_ + 512);                                \
        }                                                                          \
        __VA_ARGS__;                                                               \
        __builtin_amdgcn_s_barrier();                                              \
        asm volatile("s_waitcnt lgkmcnt(0)" ::: "memory");                         \
        __builtin_amdgcn_sched_barrier(0);                                         \
        __builtin_amdgcn_s_setprio(1);                                             \
        _Pragma("unroll") for (int tt = 0; tt < 3; ++tt)                           \
            _Pragma("unroll") for (int mi = 0; mi < 4; ++mi) {                     \
                acc[mi][0] = __builtin_amdgcn_mfma_f32_32x32x16_bf16(av[tt][mi], bv[tt][0], acc[mi][0], 0, 0, 0); \
                acc[mi][1] = __builtin_amdgcn_mfma_f32_32x32x16_bf16(av[tt][mi], bv[tt][1], acc[mi][1], 0, 0, 0); \
            }                                                                      \
        __builtin_amdgcn_s_setprio(0);                                             \
    }

__global__ __launch_bounds__(512, 2)
void conv_kernel(const unsigned short* __restrict__ xs2,
                 const unsigned short* __restrict__ wb2,
                 const float* __restrict__ deco,
                 float* __restrict__ out) {
    extern __shared__ unsigned short smem[];
    unsigned short* w0 = smem;
    unsigned short* x0 = smem + W_SH;
    unsigned short* w1 = smem + W_SH + X_SH;
    unsigned short* x1 = smem + 2 * W_SH + X_SH;

    int tid  = threadIdx.x;
    int lane = tid & 63, wave = tid >> 6;
    int r31  = lane & 31, hi = lane >> 5;

    int blk = blockIdx.x;
    int bi = blk & 15, ot = (blk >> 4) & 3, yt = blk >> 6;
    int o0 = ot * 128, y0 = yt * 8;

    // zero X buffers once (halo cols + out-of-image rows stay 0 forever)
    {
        u32x4 z = {0u, 0u, 0u, 0u};
        for (int idx = tid; idx < X_SH / 8; idx += 512) {
            *(u32x4*)(x0 + idx * 8) = z;
            *(u32x4*)(x1 + idx * 8) = z;
        }
    }
    __syncthreads();

    const char* wsrc = (const char*)wb2 + (size_t)ot * 32 * 36 * 64 * 16;
    const char* xsrc = (const char*)xs2 + (size_t)bi * 32 * 64 * 128 * 16;

    // X read bases (XOR-swizzle folded in; bijective mod-8 slot phases)
    int boff[3];
    #pragma unroll
    for (int dx = 0; dx < 3; ++dx) {
        int cb = r31 + dx;
        boff[dx] = cb * 16 + (hi ^ ((cb >> 2) & 1)) * 8;  // shorts; + rr*1056 + ni*512
    }

    f32x16 acc[4][2];
    #pragma unroll
    for (int mi = 0; mi < 4; ++mi)
        #pragma unroll
        for (int ni = 0; ni < 2; ++ni)
            #pragma unroll
            for (int k = 0; k < 16; ++k) acc[mi][ni][k] = 0.f;

    ISSUE(0, w0, x0);

    #pragma unroll 1
    for (int c = 0; c < 32; c += 2) {
        VMBAR();                               // chunk-c loads landed everywhere
        PHASE(w0, x0, 0, ISSUE(c + 1, w1, x1));
        PHASE(w0, x0, 1);
        PHASE(w0, x0, 2);
        VMBAR();
        PHASE(w1, x1, 0, if (c + 2 < 32) ISSUE(c + 2, w0, x0));
        PHASE(w1, x1, 1);
        PHASE(w1, x1, 2);
    }

    // epilogue: scale by deco, store f32
    int y = y0 + wave;
    const float* dcp = deco + bi * NCH + o0;
    #pragma unroll
    for (int mi = 0; mi < 4; ++mi) {
        #pragma unroll
        for (int r = 0; r < 16; ++r) {
            int ol = mi * 32 + (r & 3) + 8 * (r >> 2) + 4 * hi;
            float dc = dcp[ol];
            float* orow = out + ((size_t)(bi * NCH + o0 + ol) * 64 + y) * 64 + r31;
            orow[0]  = acc[mi][0][r] * dc;
            orow[32] = acc[mi][1][r] * dc;
        }
    }
}

extern "C" void kernel_launch(void* const* d_in, const int* in_sizes, int n_in,
                              void* d_out, int out_size, void* d_ws, size_t ws_size,
                              hipStream_t stream) {
    const float* x      = (const float*)d_in[0];
    const float* style  = (const float*)d_in[1];
    const float* weight = (const float*)d_in[2];
    const float* fc_w   = (const float*)d_in[3];
    const float* fc_b   = (const float*)d_in[4];
    float* out = (float*)d_out;

    char* ws = (char*)d_ws;
    float* s    = (float*)(ws);
    float* deco = (float*)(ws + 32768);
    float* q    = (float*)(ws + 65536);
    unsigned short* wb2 = (unsigned short*)(ws + 1114112);
    unsigned short* xs2 = (unsigned short*)(ws + 5832704);

    (void)hipFuncSetAttribute((const void*)conv_kernel,
                              hipFuncAttributeMaxDynamicSharedMemorySize, 115968);

    calc_s_kernel<<<2048, 256, 0, stream>>>(style, fc_w, fc_b, s);
    calc_q_wb2_kernel<<<512, 512, 0, stream>>>(weight, q, wb2);
    calc_deco_kernel<<<2048, 256, 0, stream>>>(q, s, deco);
    scale_x2_kernel<<<512, 256, 0, stream>>>(x, s, xs2);
    conv_kernel<<<512, 512, 115968, stream>>>(xs2, wb2, deco, out);
}

// Round 4
// 298.718 us; speedup vs baseline: 1.0233x; 1.0233x over previous
//
#include <hip/hip_runtime.h>
#include <hip/hip_bf16.h>

// ModulatedConv2d B=16, Cin=Cout=512, 3x3, 64x64.
// out = deco[b,o] * conv2d(x*s[b,i], W*gain), weights shared across batch.
// Conv: 32x32x16 bf16 MFMA. Block = (bi, 64-o tile, 16-row tile), 8 waves;
// wave = 2 output rows x 64o x 64x (acc 2x2x2 f32x16 = 128 VGPR).
// W-frags reused across rows; X-rows reused across taps -> 42 ds_read_b128
// per 72 MFMA (LDS pipe below MFMA pipe). All LDS reads lane-linear 16B
// contiguous (conflict-free); staging via global_load_lds (linear dest).
//
// ws layout:
//   s    : f32[16*512]                 @ 0
//   deco : f32[16*512]                 @ 32768
//   q    : f32[512*512]                @ 65536
//   wb2  : bf16 frag-linear W          @ 1114112   (8 ot x 32 chunk x 18 (mi,t) x 64 lane x 16B)
//   xs2  : bf16 khalf-major X          @ 5832704   (16 b x 32 chunk x 64 y x 2 h x 64 xpos x 16B)

#define NCH 512

static constexpr float FC_GAIN_C = 0.04419417382415922f;   // 1/sqrt(512)
static constexpr float W_GAIN_C  = 0.014731391274719742f;  // 1/sqrt(512*9)

typedef float        f32x4  __attribute__((ext_vector_type(4)));
typedef float        f32x16 __attribute__((ext_vector_type(16)));
typedef short        s16x8  __attribute__((ext_vector_type(8)));
typedef unsigned int u32x4  __attribute__((ext_vector_type(4)));

__device__ __forceinline__ unsigned short f2bf(float f) {
    __hip_bfloat16 h = __float2bfloat16(f);
    return *reinterpret_cast<unsigned short*>(&h);
}

__device__ __forceinline__ void gld16(const void* g, void* l) {
    __builtin_amdgcn_global_load_lds(
        (const __attribute__((address_space(1))) unsigned int*)g,
        (__attribute__((address_space(3))) unsigned int*)(l), 16, 0, 0);
}

// ---------------- K1: s[b,i] = style[b,:] . fc_w[i,:] * FC_GAIN + fc_b[i] ----------------
__global__ void calc_s_kernel(const float* __restrict__ style,
                              const float* __restrict__ fc_w,
                              const float* __restrict__ fc_b,
                              float* __restrict__ s) {
    int gw   = (blockIdx.x * blockDim.x + threadIdx.x) >> 6;
    int lane = threadIdx.x & 63;
    int b = gw >> 9;
    int i = gw & 511;
    const float* st = style + b * NCH;
    const float* fw = fc_w + (size_t)i * NCH;
    float sum = 0.f;
    #pragma unroll
    for (int k = 0; k < NCH / 64; ++k)
        sum += st[lane + 64 * k] * fw[lane + 64 * k];
    #pragma unroll
    for (int off = 32; off >= 1; off >>= 1)
        sum += __shfl_xor(sum, off, 64);
    if (lane == 0)
        s[b * NCH + i] = sum * FC_GAIN_C + fc_b[i];
}

// ---------------- K2: q[o,i] and fragment-linear wb2 ------------------------------------
// wb2 unit: (((ot*32+chunk)*18 + mi*9 + t)*64 + lane)*8 + e
// content: W[o = ot*64 + mi*32 + (lane&31)][ci = chunk*16 + (lane>>5)*8 + e][tap t] * gain
__global__ void calc_q_wb2_kernel(const float* __restrict__ weight,
                                  float* __restrict__ q,
                                  unsigned short* __restrict__ wb2) {
    int o = blockIdx.x;        // 0..511
    int i = threadIdx.x;       // 0..511 (ci)
    int orel = o & 63, ot = o >> 6;
    int mi = orel >> 5, l31 = orel & 31;
    int chunk = i >> 4, kk = i & 15;
    int lane = (kk >> 3) * 32 + l31, e = kk & 7;
    const float* wp = weight + ((size_t)o * NCH + i) * 9;
    float qs = 0.f;
    #pragma unroll
    for (int t = 0; t < 9; ++t) {
        float v = wp[t] * W_GAIN_C;
        qs += v * v;
        wb2[((((size_t)(ot * 32 + chunk) * 18) + mi * 9 + t) * 64 + lane) * 8 + e] = f2bf(v);
    }
    q[(size_t)o * NCH + i] = qs;
}

// ---------------- K3: deco[b,o] = rsqrt( sum_i q[o,i]*s[b,i]^2 + 1e-8 ) -----------------
__global__ void calc_deco_kernel(const float* __restrict__ q,
                                 const float* __restrict__ s,
                                 float* __restrict__ deco) {
    int gw   = (blockIdx.x * blockDim.x + threadIdx.x) >> 6;
    int lane = threadIdx.x & 63;
    int b = gw >> 9;
    int o = gw & 511;
    const float* qp = q + (size_t)o * NCH;
    const float* sp = s + b * NCH;
    float sum = 0.f;
    #pragma unroll
    for (int k = 0; k < NCH / 64; ++k) {
        float sv = sp[lane + 64 * k];
        sum += qp[lane + 64 * k] * sv * sv;
    }
    #pragma unroll
    for (int off = 32; off >= 1; off >>= 1)
        sum += __shfl_xor(sum, off, 64);
    if (lane == 0)
        deco[b * NCH + o] = rsqrtf(sum + 1e-8f);
}

// ---------------- K4: xs2 = bf16(x * s), NCHW -> khalf-major slot layout ------------------
// xs2 unit: (((b*32+chunk)*64 + y)*2 + h)*64 + xpos ; content ch [chunk*16+h*8, +8) at (y,xpos)
__global__ __launch_bounds__(256)
void scale_x2_kernel(const float* __restrict__ x, const float* __restrict__ s,
                     unsigned short* __restrict__ xs2) {
    __shared__ float tlf[2][64][17];
    int blk = blockIdx.x;          // 512 = bi*32 + chunk
    int chunk = blk & 31, bi = blk >> 5;
    int t = threadIdx.x;
    int ch0 = chunk * 16;
    int cl = t >> 4, xq = (t & 15) * 4;
    float sv = s[bi * NCH + ch0 + cl];
    const float* xp = x + ((size_t)(bi * NCH + ch0 + cl)) * 4096 + xq;
    int p = t >> 7, tt = t & 127;
    int hf = tt >> 6, xpos = tt & 63;
    unsigned short* xout = xs2 + (size_t)(bi * 32 + chunk) * 64 * 2 * 64 * 8;
    for (int y2 = 0; y2 < 64; y2 += 2) {
        f32x4 a0 = *(const f32x4*)(xp + (size_t)y2 * 64);
        f32x4 a1 = *(const f32x4*)(xp + (size_t)(y2 + 1) * 64);
        #pragma unroll
        for (int j = 0; j < 4; ++j) {
            tlf[0][xq + j][cl] = a0[j] * sv;
            tlf[1][xq + j][cl] = a1[j] * sv;
        }
        __syncthreads();
        const float* src = &tlf[p][xpos][hf * 8];
        u32x4 v;
        #pragma unroll
        for (int j = 0; j < 4; ++j)
            v[j] = (unsigned)f2bf(src[2 * j]) | ((unsigned)f2bf(src[2 * j + 1]) << 16);
        *(u32x4*)(xout + (((size_t)(y2 + p) * 2 + hf) * 64 + xpos) * 8) = v;
        __syncthreads();
    }
}

// ---------------- K5: conv --------------------------------------------------------------
// LDS per buffer: W [18 (mi,t)][64 lane][16B] = 18432 B, X [18 rows][2 h][66 P][16B] = 38016 B.
#define W_SH 9216    // shorts per W buffer
#define X_SH 19008   // shorts per X buffer

#define ISSUE(nc, WN, XN)                                                          \
    {                                                                              \
        _Pragma("unroll") for (int j = 0; j < 7; ++j) {                            \
            int id = wave + j * 8;                                                 \
            if (id < 36) {                                                         \
                int r_ = id >> 1, hf = id & 1, gy = y0 - 1 + r_;                   \
                if (gy >= 0 && gy < 64)                                            \
                    gld16(xsrc + ((((size_t)(nc) * 64 + gy) * 2 + hf) * 64 + lane) * 16, \
                          (XN) + r_ * 1056 + hf * 528 + 8);                        \
            } else if (id < 54) {                                                  \
                int u = id - 36;                                                   \
                gld16(wsrc + (((size_t)(nc) * 18 + u) * 64 + lane) * 16,           \
                      (WN) + u * 512);                                             \
            }                                                                      \
        }                                                                          \
    }

#define VMBAR()                                                                    \
    {                                                                              \
        asm volatile("s_waitcnt vmcnt(0)" ::: "memory");                           \
        __builtin_amdgcn_s_barrier();                                              \
        __builtin_amdgcn_sched_barrier(0);                                         \
    }

#define LOADB(DST, XC, RR)                                                         \
    _Pragma("unroll") for (int dx = 0; dx < 3; ++dx)                               \
        _Pragma("unroll") for (int ni = 0; ni < 2; ++ni)                           \
            DST[dx][ni] = *(const s16x8*)((XC) + (RR) * 1056 + bofs[dx][ni]);

#define LOADA(DST, WC, K)                                                          \
    _Pragma("unroll") for (int dx = 0; dx < 3; ++dx)                               \
        _Pragma("unroll") for (int mi = 0; mi < 2; ++mi)                           \
            DST[dx][mi] = *(const s16x8*)((WC) + ((mi * 9 + 3 * (K) + dx) << 9) + (lane << 3));

#define MMA(AV, B0, B1)                                                            \
    _Pragma("unroll") for (int dx = 0; dx < 3; ++dx)                               \
        _Pragma("unroll") for (int mi = 0; mi < 2; ++mi)                           \
            _Pragma("unroll") for (int ni = 0; ni < 2; ++ni) {                     \
                acc[0][mi][ni] = __builtin_amdgcn_mfma_f32_32x32x16_bf16(          \
                    AV[dx][mi], B0[dx][ni], acc[0][mi][ni], 0, 0, 0);              \
                acc[1][mi][ni] = __builtin_amdgcn_mfma_f32_32x32x16_bf16(          \
                    AV[dx][mi], B1[dx][ni], acc[1][mi][ni], 0, 0, 0);              \
            }

// rolling 2-row B window: rows rbase..rbase+3; W frags shared by both output rows
#define COMPUTE(WC, XC, ...)                                                       \
    {                                                                              \
        s16x8 Pb[3][2], Qb[3][2], Af[3][2];                                        \
        LOADB(Pb, XC, rbase + 0);                                                  \
        LOADB(Qb, XC, rbase + 1);                                                  \
        LOADA(Af, WC, 0);                                                          \
        __VA_ARGS__;                                                               \
        MMA(Af, Pb, Qb);                                                           \
        LOADB(Pb, XC, rbase + 2);                                                  \
        LOADA(Af, WC, 1);                                                          \
        MMA(Af, Qb, Pb);                                                           \
        LOADB(Qb, XC, rbase + 3);                                                  \
        LOADA(Af, WC, 2);                                                          \
        MMA(Af, Pb, Qb);                                                           \
    }

__global__ __launch_bounds__(512, 2)
void conv_kernel(const unsigned short* __restrict__ xs2,
                 const unsigned short* __restrict__ wb2,
                 const float* __restrict__ deco,
                 float* __restrict__ out) {
    extern __shared__ unsigned short smem[];
    unsigned short* w0 = smem;
    unsigned short* x0 = smem + W_SH;
    unsigned short* w1 = smem + W_SH + X_SH;
    unsigned short* x1 = smem + 2 * W_SH + X_SH;

    int tid  = threadIdx.x;
    int lane = tid & 63, wave = tid >> 6;
    int r31  = lane & 31, hi = lane >> 5;

    int blk = blockIdx.x;
    int swz = (blk & 7) * 64 + (blk >> 3);     // XCD-chunked (512 % 8 == 0, bijective)
    int bi = swz >> 5, ot = (swz >> 2) & 7, yt = swz & 3;
    int o0 = ot * 64, y0 = yt * 16;
    int rbase = 2 * wave;

    // zero X buffers once: halo granules (P=0,65) and out-of-image rows stay 0
    {
        u32x4 z = {0u, 0u, 0u, 0u};
        for (int idx = tid; idx < X_SH / 8; idx += 512) {
            *(u32x4*)(x0 + idx * 8) = z;
            *(u32x4*)(x1 + idx * 8) = z;
        }
    }
    __syncthreads();

    const char* wsrc = (const char*)wb2 + (size_t)ot * 32 * 18 * 64 * 16;
    const char* xsrc = (const char*)xs2 + (size_t)bi * 32 * 64 * 2 * 64 * 16;

    // lane-linear B read offsets (shorts): row term added per read
    int bofs[3][2];
    #pragma unroll
    for (int dx = 0; dx < 3; ++dx)
        #pragma unroll
        for (int ni = 0; ni < 2; ++ni)
            bofs[dx][ni] = hi * 528 + (r31 + dx + 32 * ni) * 8;

    f32x16 acc[2][2][2];
    #pragma unroll
    for (int r = 0; r < 2; ++r)
        #pragma unroll
        for (int mi = 0; mi < 2; ++mi)
            #pragma unroll
            for (int ni = 0; ni < 2; ++ni)
                #pragma unroll
                for (int k = 0; k < 16; ++k) acc[r][mi][ni][k] = 0.f;

    ISSUE(0, w0, x0);

    #pragma unroll 1
    for (int c = 0; c < 32; c += 2) {
        VMBAR();                                   // chunk-c data landed everywhere
        COMPUTE(w0, x0, ISSUE(c + 1, w1, x1));
        VMBAR();
        COMPUTE(w1, x1, if (c + 2 < 32) ISSUE(c + 2, w0, x0));
    }

    // epilogue: scale by deco, store f32
    const float* dcp = deco + bi * NCH + o0;
    #pragma unroll
    for (int r = 0; r < 2; ++r) {
        int y = y0 + 2 * wave + r;
        #pragma unroll
        for (int mi = 0; mi < 2; ++mi) {
            #pragma unroll
            for (int rg = 0; rg < 16; ++rg) {
                int ol = mi * 32 + (rg & 3) + 8 * (rg >> 2) + 4 * hi;
                float dc = dcp[ol];
                float* orow = out + ((size_t)(bi * NCH + o0 + ol) * 64 + y) * 64 + r31;
                orow[0]  = acc[r][mi][0][rg] * dc;
                orow[32] = acc[r][mi][1][rg] * dc;
            }
        }
    }
}

extern "C" void kernel_launch(void* const* d_in, const int* in_sizes, int n_in,
                              void* d_out, int out_size, void* d_ws, size_t ws_size,
                              hipStream_t stream) {
    const float* x      = (const float*)d_in[0];
    const float* style  = (const float*)d_in[1];
    const float* weight = (const float*)d_in[2];
    const float* fc_w   = (const float*)d_in[3];
    const float* fc_b   = (const float*)d_in[4];
    float* out = (float*)d_out;

    char* ws = (char*)d_ws;
    float* s    = (float*)(ws);
    float* deco = (float*)(ws + 32768);
    float* q    = (float*)(ws + 65536);
    unsigned short* wb2 = (unsigned short*)(ws + 1114112);
    unsigned short* xs2 = (unsigned short*)(ws + 5832704);

    (void)hipFuncSetAttribute((const void*)conv_kernel,
                              hipFuncAttributeMaxDynamicSharedMemorySize, 112896);

    calc_s_kernel<<<2048, 256, 0, stream>>>(style, fc_w, fc_b, s);
    calc_q_wb2_kernel<<<512, 512, 0, stream>>>(weight, q, wb2);
    calc_deco_kernel<<<2048, 256, 0, stream>>>(q, s, deco);
    scale_x2_kernel<<<512, 256, 0, stream>>>(x, s, xs2);
    conv_kernel<<<512, 512, 112896, stream>>>(xs2, wb2, deco, out);
}